// Round 10
// baseline (1143.099 us; speedup 1.0000x reference)
//
#include <hip/hip_runtime.h>
#include <math.h>

typedef short bf16x8 __attribute__((ext_vector_type(8)));
typedef float f32x4  __attribute__((ext_vector_type(4)));
typedef int   int4v  __attribute__((ext_vector_type(4)));

#define GLOAD_LDS16(SRC, DST) \
  __builtin_amdgcn_global_load_lds((const __attribute__((address_space(1))) void*)(SRC), \
      (__attribute__((address_space(3))) void*)(DST), 16, 0, 0)

#define WAITVM(N) asm volatile("s_waitcnt vmcnt(" #N ")" ::: "memory")
#define WAITLGKM0 asm volatile("s_waitcnt lgkmcnt(0)" ::: "memory")
#define BARRIER() do { __builtin_amdgcn_s_barrier(); asm volatile("" ::: "memory"); } while (0)

__device__ __forceinline__ unsigned short f2bf(float f) {
  union { float f; unsigned u; } v; v.f = f;
  unsigned r = v.u + 0x7FFFu + ((v.u >> 16) & 1u);   // RNE
  return (unsigned short)(r >> 16);
}
__device__ __forceinline__ float bf2f(unsigned short s) {
  union { unsigned u; float f; } v; v.u = ((unsigned)s) << 16;
  return v.f;
}
__device__ __forceinline__ unsigned pk2bf(float lo, float hi) {
  unsigned r;
  asm("v_cvt_pk_bf16_f32 %0, %1, %2" : "=v"(r) : "v"(lo), "v"(hi));  // RNE
  return r;
}

// Granule layout: [128 x 32k] bf16 tile = 512 granules of 16B.
// granule g = s*64 + l: row = s*16 + (l&15), k8 = (l>>4)*8.
// h1_pk / W1T_pk / WabT_pk: panel P = rowpanel*16 + coltile (x512 granules).

// ---------------- weight pack (unchanged)
__global__ void carp_wpack(const float* __restrict__ W1, const float* __restrict__ Wa,
                           const float* __restrict__ Wb,
                           unsigned short* __restrict__ W1T_pk, unsigned short* __restrict__ WabT_pk) {
  int t = blockIdx.x * 256 + threadIdx.x;
  int mat = t >> 15;
  int gid = t & 32767;
  int g = gid & 511;
  int kt = (gid >> 9) & 15;
  int p = gid >> 13;
  int s = g >> 6, l = g & 63;
  int j = p * 128 + s * 16 + (l & 15);
  int k = kt * 32 + (l >> 4) * 8;
  unsigned short v[8];
  if (mat == 0) {
#pragma unroll
    for (int e = 0; e < 8; ++e) v[e] = f2bf(W1[(size_t)(k + e) * 512 + j]);
    *(uint4*)(W1T_pk + (size_t)gid * 8) = *(const uint4*)v;
  } else {
    int d = j >> 1;
    const float* Wx = (j & 1) ? Wb : Wa;
#pragma unroll
    for (int e = 0; e < 8; ++e) v[e] = f2bf(Wx[(size_t)(k + e) * 256 + d]);
    *(uint4*)(WabT_pk + (size_t)gid * 8) = *(const uint4*)v;
  }
}

// ---------------- GEMM1 (unchanged from R9, passing)
__launch_bounds__(512, 4)
__global__ void carp_gemm1(const float* __restrict__ h, const unsigned short* __restrict__ W1T_pk,
                           const float* __restrict__ b1, unsigned short* __restrict__ h1_pk) {
  __shared__ __align__(16) unsigned short lds[32768];   // 64KB
  int bid0 = blockIdx.x;
  int bid = (bid0 & 7) * 256 + (bid0 >> 3);
  int bn = bid & 3, bm = bid >> 2;
  int brow = bm * 256;
  int tid = threadIdx.x, lane = tid & 63, wid = tid >> 6;
  int wr = wid >> 1, wc = wid & 1;

  f32x4 acc[4][4] = {};
  float4 ar[4];

  int arow = lane >> 3;
  int ak4 = lane & 7;
  const float* hbase = h + (size_t)(brow + wid * 32 + arow) * 512 + ak4 * 4;
  int aw_base = ((ak4 >> 1) * 16 + arow) * 16 + (ak4 & 1) * 8 + wid * 2048;

#define G1_LOADA(T) do { \
  _Pragma("unroll") for (int q = 0; q < 4; ++q) \
    ar[q] = *(const float4*)(hbase + (size_t)(q * 8) * 512 + (T) * 32); \
  } while (0)
#define G1_WRITEA(T) do { \
  char* dstA = (char*)lds + ((T) & 1) * 16384; \
  _Pragma("unroll") for (int q = 0; q < 4; ++q) { \
    uint2 wv; wv.x = pk2bf(ar[q].x, ar[q].y); wv.y = pk2bf(ar[q].z, ar[q].w); \
    *(uint2*)(dstA + aw_base + (q >> 1) * 1024 + (q & 1) * 128) = wv; \
  } } while (0)
#define G1_STAGEB(T, BUF) \
  GLOAD_LDS16(W1T_pk + ((size_t)(bn * 16 + (T)) * 512 + wid * 64 + lane) * 8, \
              (char*)lds + 32768 + (BUF) * 8192 + (size_t)wid * 1024)

  G1_LOADA(0);
  WAITVM(0);
  G1_WRITEA(0);
  G1_STAGEB(0, 0);
  G1_LOADA(1);
  WAITLGKM0;

#pragma unroll
  for (int kt = 0; kt < 16; ++kt) {
    if (kt + 1 < 16) G1_STAGEB(kt + 1, (kt + 1) & 1);
    if (kt < 15) { WAITVM(5); } else { WAITVM(0); }
    BARRIER();
    const char* Ab = (const char*)lds + (kt & 1) * 16384;
    const char* Bb = (const char*)lds + 32768 + (kt & 1) * 8192;
    bf16x8 afr[4], bfr[4];
#pragma unroll
    for (int m = 0; m < 4; ++m)
      afr[m] = *(const bf16x8*)(Ab + (size_t)((wr * 4 + m) * 64 + lane) * 16);
#pragma unroll
    for (int n = 0; n < 4; ++n)
      bfr[n] = *(const bf16x8*)(Bb + (size_t)((wc * 4 + n) * 64 + lane) * 16);
#pragma unroll
    for (int m = 0; m < 4; ++m)
#pragma unroll
      for (int n = 0; n < 4; ++n)
        acc[m][n] = __builtin_amdgcn_mfma_f32_16x16x32_bf16(afr[m], bfr[n], acc[m][n], 0, 0, 0);
    if (kt + 1 < 16) {
      WAITVM(1);
      G1_WRITEA(kt + 1);
    }
    if (kt + 2 < 16) G1_LOADA(kt + 2);
    WAITLGKM0;
    BARRIER();
  }
#undef G1_LOADA
#undef G1_WRITEA
#undef G1_STAGEB

  unsigned short* img = lds;
#pragma unroll
  for (int n = 0; n < 4; ++n) {
    int cl = wc * 64 + n * 16 + (lane & 15);
    float bias = b1[bn * 128 + cl];
    int ktc = cl >> 5, c32 = cl & 31;
#pragma unroll
    for (int m = 0; m < 4; ++m)
#pragma unroll
      for (int j = 0; j < 4; ++j) {
        int r = wr * 64 + m * 16 + (lane >> 4) * 4 + j;
        float v = acc[m][n][j] + bias;
        v = v > 0.f ? v : 0.f;
        int gidx = (r >> 7) * 2048 + ktc * 512 + ((r & 127) >> 4) * 64 + (c32 >> 3) * 16 + (r & 15);
        img[(size_t)gidx * 8 + (c32 & 7)] = f2bf(v);
      }
  }
  __syncthreads();
#pragma unroll
  for (int i = 0; i < 8; ++i) {
    int g = i * 512 + tid;
    int P = (2 * bm + (g >> 11)) * 16 + bn * 4 + ((g >> 9) & 3);
    *(uint4*)(h1_pk + ((size_t)P * 512 + (g & 511)) * 8) = *(const uint4*)(img + (size_t)g * 8);
  }
}

#define G2_STAGE(T, BUF) do { \
  _Pragma("unroll") for (int q = 0; q < 2; ++q) { \
    int c = wid * 2 + q; \
    int P = (2 * bm + (c >> 3)) * 16 + (T); \
    GLOAD_LDS16(h1_pk + ((size_t)P * 512 + (c & 7) * 64 + lane) * 8, \
                (char*)lds + (BUF) * 16384 + (size_t)c * 1024); \
  } \
  GLOAD_LDS16(WabT_pk + ((size_t)(bn * 16 + (T)) * 512 + wid * 64 + lane) * 8, \
              (char*)lds + 32768 + (BUF) * 8192 + (size_t)wid * 1024); \
  } while (0)

// ---------------- GEMM2 (unchanged from R9, passing)
__launch_bounds__(512, 4)
__global__ void carp_gemm2(const unsigned short* __restrict__ h1_pk, const unsigned short* __restrict__ WabT_pk,
                           const float* __restrict__ ba, const float* __restrict__ bb,
                           const float* __restrict__ Wc, float* __restrict__ A_part) {
  __shared__ __align__(16) unsigned short lds[24576];
  int bid0 = blockIdx.x;
  int bid = (bid0 & 7) * 256 + (bid0 >> 3);
  int bn = bid & 3, bm = bid >> 2;
  int tid = threadIdx.x, lane = tid & 63, wid = tid >> 6;
  int wr = wid >> 1, wc = wid & 1;

  f32x4 acc[4][4] = {};

  G2_STAGE(0, 0);
#pragma unroll
  for (int kt = 0; kt < 16; ++kt) {
    if (kt + 1 < 16) G2_STAGE(kt + 1, (kt + 1) & 1);
    if (kt + 1 < 16) { WAITVM(3); } else { WAITVM(0); }
    BARRIER();
    const char* Ab = (const char*)lds + (kt & 1) * 16384;
    const char* Bb = (const char*)lds + 32768 + (kt & 1) * 8192;
    bf16x8 afr[4], bfr[4];
#pragma unroll
    for (int m = 0; m < 4; ++m)
      afr[m] = *(const bf16x8*)(Ab + (size_t)((wr * 4 + m) * 64 + lane) * 16);
#pragma unroll
    for (int n = 0; n < 4; ++n)
      bfr[n] = *(const bf16x8*)(Bb + (size_t)((wc * 4 + n) * 64 + lane) * 16);
#pragma unroll
    for (int m = 0; m < 4; ++m)
#pragma unroll
      for (int n = 0; n < 4; ++n)
        acc[m][n] = __builtin_amdgcn_mfma_f32_16x16x32_bf16(afr[m], bfr[n], acc[m][n], 0, 0, 0);
    WAITLGKM0;
    BARRIER();
  }

  int brow = bm * 256, bcol = bn * 128;
  float rowpart[4][4] = {};
#pragma unroll
  for (int n = 0; n < 4; ++n) {
    int cg = bcol + wc * 64 + n * 16 + (lane & 15);
    int d = cg >> 1;
    float bias = (cg & 1) ? bb[d] : ba[d];
    float wcd = Wc[d];
#pragma unroll
    for (int m = 0; m < 4; ++m)
#pragma unroll
      for (int j = 0; j < 4; ++j) {
        float v = acc[m][n][j] + bias;
        float av = (cg & 1) ? (1.f / (1.f + expf(-v))) : tanhf(v);
        float pv = av * __shfl_xor(av, 1, 64);
        rowpart[m][j] += pv * wcd;
      }
  }
#pragma unroll
  for (int m = 0; m < 4; ++m)
#pragma unroll
    for (int j = 0; j < 4; ++j) {
      float t = rowpart[m][j];
      t += __shfl_xor(t, 2, 64);
      t += __shfl_xor(t, 4, 64);
      t += __shfl_xor(t, 8, 64);
      rowpart[m][j] = t;
    }
  if ((lane & 15) == 0) {
    int slot = bn * 2 + wc;
#pragma unroll
    for (int m = 0; m < 4; ++m)
#pragma unroll
      for (int j = 0; j < 4; ++j) {
        int row = brow + wr * 64 + m * 16 + (lane >> 4) * 4 + j;
        A_part[(size_t)row * 8 + slot] = rowpart[m][j];
      }
  }
}

// ---------------- ABLATION variants of the gemm2 structure (write scratch only)
// MODE 1: no staging (reads+MFMA+barriers)   MODE 2: no MFMA (staging+reads+barriers)
// MODE 3: no ds_read (staging+MFMA+barriers) MODE 4: barriers only
// MODE 5: no barriers/waits (reads+MFMA, single buffer)
template<int MODE>
__launch_bounds__(512, 4)
__global__ void abl_gemm2(const unsigned short* __restrict__ h1_pk,
                          const unsigned short* __restrict__ WabT_pk,
                          float* __restrict__ abl_out) {
  __shared__ __align__(16) unsigned short lds[24576];
  int bid0 = blockIdx.x;
  int bid = (bid0 & 7) * 256 + (bid0 >> 3);
  int bn = bid & 3, bm = bid >> 2;
  int tid = threadIdx.x, lane = tid & 63, wid = tid >> 6;
  int wr = wid >> 1, wc = wid & 1;

  f32x4 acc[4][4] = {};
  int ssink = 0;
  bf16x8 cafr[4], cbfr[4];
#pragma unroll
  for (int m = 0; m < 4; ++m)
#pragma unroll
    for (int e = 0; e < 8; ++e) { cafr[m][e] = (short)(lane + m * 7 + e); cbfr[m][e] = (short)(lane * 2 + m + e * 3); }

  if (MODE != 4) { G2_STAGE(0, 0); }
  if (MODE == 1 || MODE == 5) { G2_STAGE(1, 1); WAITVM(0); }
  if (MODE == 5) BARRIER();

#pragma unroll
  for (int kt = 0; kt < 16; ++kt) {
    if (MODE == 2 || MODE == 3) {
      if (kt + 1 < 16) { G2_STAGE(kt + 1, (kt + 1) & 1); WAITVM(3); } else { WAITVM(0); }
    }
    if (MODE != 5) BARRIER();
    if (MODE != 4) {
      const char* Ab = (const char*)lds + ((MODE == 5 ? 0 : (kt & 1)) * 16384);
      const char* Bb = (const char*)lds + 32768 + ((MODE == 5 ? 0 : (kt & 1)) * 8192);
      bf16x8 afr[4], bfr[4];
      if (MODE == 3) {
#pragma unroll
        for (int m = 0; m < 4; ++m) { afr[m] = cafr[m]; bfr[m] = cbfr[m]; }
      } else {
#pragma unroll
        for (int m = 0; m < 4; ++m)
          afr[m] = *(const bf16x8*)(Ab + (size_t)((wr * 4 + m) * 64 + lane) * 16);
#pragma unroll
        for (int n = 0; n < 4; ++n)
          bfr[n] = *(const bf16x8*)(Bb + (size_t)((wc * 4 + n) * 64 + lane) * 16);
      }
      if (MODE == 2) {
#pragma unroll
        for (int m = 0; m < 4; ++m) {
          asm volatile("" :: "v"(*(const int4v*)&afr[m]), "v"(*(const int4v*)&bfr[m]));
          ssink += afr[m][0] + bfr[m][0];
        }
      } else {
#pragma unroll
        for (int m = 0; m < 4; ++m)
#pragma unroll
          for (int n = 0; n < 4; ++n)
            acc[m][n] = __builtin_amdgcn_mfma_f32_16x16x32_bf16(afr[m], bfr[n], acc[m][n], 0, 0, 0);
      }
    }
    if (MODE != 5 && MODE != 4) WAITLGKM0;
    if (MODE != 5) BARRIER();
  }
  float sv = acc[0][0][0] + acc[1][1][1] + acc[2][2][2] + acc[3][3][3] + (float)ssink;
  if (lane == 0) abl_out[bid * 8 + wid] = sv;
}

// ---------------- ablation: BK=64 (half the barrier pairs; 96KB LDS -> 1 block/CU)
__launch_bounds__(512, 2)
__global__ void abl_bk64(const unsigned short* __restrict__ h1_pk,
                         const unsigned short* __restrict__ WabT_pk,
                         float* __restrict__ abl_out) {
  __shared__ __align__(16) unsigned short lds[49152];   // A dbuf [0,64K); B dbuf [64K,96K)
  int bid0 = blockIdx.x;
  int bid = (bid0 & 7) * 256 + (bid0 >> 3);
  int bn = bid & 3, bm = bid >> 2;
  int tid = threadIdx.x, lane = tid & 63, wid = tid >> 6;
  int wr = wid >> 1, wc = wid & 1;

  f32x4 acc[4][4] = {};

#define BK64_STAGE(T32, HALF, BUF) do { \
  _Pragma("unroll") for (int q = 0; q < 2; ++q) { \
    int c = wid * 2 + q; \
    int P = (2 * bm + (c >> 3)) * 16 + (T32); \
    GLOAD_LDS16(h1_pk + ((size_t)P * 512 + (c & 7) * 64 + lane) * 8, \
                (char*)lds + (BUF) * 32768 + (HALF) * 16384 + (size_t)c * 1024); \
  } \
  GLOAD_LDS16(WabT_pk + ((size_t)(bn * 16 + (T32)) * 512 + wid * 64 + lane) * 8, \
              (char*)lds + 65536 + (BUF) * 16384 + (HALF) * 8192 + (size_t)wid * 1024); \
  } while (0)

  BK64_STAGE(0, 0, 0); BK64_STAGE(1, 1, 0);   // 6/wave outstanding

#pragma unroll
  for (int kt = 0; kt < 8; ++kt) {
    int cur = kt & 1, nxt = cur ^ 1;
    if (kt < 7) { BK64_STAGE(2 * kt + 2, 0, nxt); BK64_STAGE(2 * kt + 3, 1, nxt); }
    if (kt < 7) { WAITVM(6); } else { WAITVM(0); }
    BARRIER();
#pragma unroll
    for (int tt = 0; tt < 2; ++tt) {
      const char* Ab = (const char*)lds + cur * 32768 + tt * 16384;
      const char* Bb = (const char*)lds + 65536 + cur * 16384 + tt * 8192;
      bf16x8 afr[4], bfr[4];
#pragma unroll
      for (int m = 0; m < 4; ++m)
        afr[m] = *(const bf16x8*)(Ab + (size_t)((wr * 4 + m) * 64 + lane) * 16);
#pragma unroll
      for (int n = 0; n < 4; ++n)
        bfr[n] = *(const bf16x8*)(Bb + (size_t)((wc * 4 + n) * 64 + lane) * 16);
#pragma unroll
      for (int m = 0; m < 4; ++m)
#pragma unroll
        for (int n = 0; n < 4; ++n)
          acc[m][n] = __builtin_amdgcn_mfma_f32_16x16x32_bf16(afr[m], bfr[n], acc[m][n], 0, 0, 0);
    }
    WAITLGKM0;
    BARRIER();
  }
#undef BK64_STAGE
  float sv = acc[0][0][0] + acc[1][1][1] + acc[2][2][2] + acc[3][3][3];
  if (lane == 0) abl_out[bid * 8 + wid] = sv;
}

// ---------------- per-bag softmax (unchanged)
__global__ void carp_softmax(const float* __restrict__ A_part, const float* __restrict__ bc,
                             float* __restrict__ A_raw_out, float* __restrict__ A_sm) {
  __shared__ float sv[8192];
  __shared__ float red[256];
  int b = blockIdx.x, tid = threadIdx.x;
  float bcv = bc[0];
  float lmax = -1e30f;
  for (int i = tid; i < 8192; i += 256) {
    const float4* p = (const float4*)(A_part + (size_t)(b * 8192 + i) * 8);
    float4 x = p[0], y = p[1];
    float s = ((x.x + x.y) + (x.z + x.w)) + ((y.x + y.y) + (y.z + y.w)) + bcv;
    sv[i] = s;
    A_raw_out[b * 8192 + i] = s;
    lmax = fmaxf(lmax, s);
  }
  red[tid] = lmax;
  for (int s = 128; s > 0; s >>= 1) { __syncthreads(); if (tid < s) red[tid] = fmaxf(red[tid], red[tid + s]); }
  __syncthreads();
  float mx = red[0];
  __syncthreads();
  float lsum = 0.f;
  for (int i = tid; i < 8192; i += 256) {
    float e = expf(sv[i] - mx);
    sv[i] = e;
    lsum += e;
  }
  red[tid] = lsum;
  for (int s = 128; s > 0; s >>= 1) { __syncthreads(); if (tid < s) red[tid] += red[tid + s]; }
  __syncthreads();
  float inv = 1.f / red[0];
  for (int i = tid; i < 8192; i += 256) A_sm[b * 8192 + i] = sv[i] * inv;
}

// ---------------- M partials (unchanged)
__global__ void carp_mkernel(const unsigned short* __restrict__ h1_pk, const float* __restrict__ A_sm,
                             float* __restrict__ Mpart) {
  __shared__ float sw[128];
  int bm = blockIdx.x;
  int tid = threadIdx.x;
  if (tid < 128) sw[tid] = A_sm[bm * 128 + tid];
  __syncthreads();
  int l = tid & 63;
  float acc[4][8] = {};
#pragma unroll
  for (int tq = 0; tq < 4; ++tq) {
    int tt = (tid >> 6) * 4 + tq;
#pragma unroll
    for (int s = 0; s < 8; ++s) {
      const unsigned short* gp = h1_pk + ((size_t)(bm * 16 + tt) * 512 + s * 64 + l) * 8;
      uint4 raw = *(const uint4*)gp;
      const unsigned short* pv = (const unsigned short*)&raw;
      float w = sw[s * 16 + (l & 15)];
#pragma unroll
      for (int e = 0; e < 8; ++e) acc[tq][e] += w * bf2f(pv[e]);
    }
  }
#pragma unroll
  for (int tq = 0; tq < 4; ++tq)
#pragma unroll
    for (int e = 0; e < 8; ++e) {
      float t = acc[tq][e];
      t += __shfl_xor(t, 1, 64);
      t += __shfl_xor(t, 2, 64);
      t += __shfl_xor(t, 4, 64);
      t += __shfl_xor(t, 8, 64);
      acc[tq][e] = t;
    }
  if ((l & 15) == 0) {
    int cc = (l >> 4) & 3;
#pragma unroll
    for (int tq = 0; tq < 4; ++tq) {
      int tt = (tid >> 6) * 4 + tq;
      float* mp = Mpart + (size_t)bm * 512 + tt * 32 + cc * 8;
#pragma unroll
      for (int e = 0; e < 8; ++e) mp[e] = acc[tq][e];
    }
  }
}

// ---------------- final (unchanged)
__global__ void carp_final(const float* __restrict__ Mpart, const float* __restrict__ Wcls,
                           const float* __restrict__ bcls, float* __restrict__ out) {
  __shared__ float ctx[512];
  int t = threadIdx.x;
  float c = 0.f;
  for (int b = 0; b < 16; ++b) {
    float s = 0.f;
    for (int p = 0; p < 64; ++p) s += Mpart[((size_t)(b * 64 + p) << 9) + t];
    out[131077 + b * 512 + t] = s;
    c += s;
  }
  ctx[t] = c * (1.f / 16.f);
  __syncthreads();
  if (t < 64) {
    float p0 = 0.f, p1 = 0.f;
    for (int hh = t; hh < 512; hh += 64) {
      float cv = ctx[hh];
      p0 += cv * Wcls[hh * 2];
      p1 += cv * Wcls[hh * 2 + 1];
    }
    for (int m = 1; m < 64; m <<= 1) { p0 += __shfl_xor(p0, m, 64); p1 += __shfl_xor(p1, m, 64); }
    if (t == 0) {
      float l0 = p0 + bcls[0], l1 = p1 + bcls[1];
      out[0] = l0; out[1] = l1;
      float mx = fmaxf(l0, l1);
      float e0 = expf(l0 - mx), e1 = expf(l1 - mx);
      float s = e0 + e1;
      out[2] = e0 / s; out[3] = e1 / s;
      out[4] = (l1 > l0) ? 1.0f : 0.0f;
    }
  }
}

extern "C" void kernel_launch(void* const* d_in, const int* in_sizes, int n_in,
                              void* d_out, int out_size, void* d_ws, size_t ws_size,
                              hipStream_t stream) {
  const float* h    = (const float*)d_in[0];
  const float* W1   = (const float*)d_in[1];
  const float* b1   = (const float*)d_in[2];
  const float* Wa   = (const float*)d_in[3];
  const float* ba   = (const float*)d_in[4];
  const float* Wb   = (const float*)d_in[5];
  const float* bb   = (const float*)d_in[6];
  const float* Wc   = (const float*)d_in[7];
  const float* bc   = (const float*)d_in[8];
  const float* Wcls = (const float*)d_in[9];
  const float* bcls = (const float*)d_in[10];
  float* out = (float*)d_out;

  char* ws = (char*)d_ws;
  unsigned short* h1_pk   = (unsigned short*)(ws);                  // 134,217,728 B
  unsigned short* W1T_pk  = (unsigned short*)(ws + 134217728);      //     524,288 B
  unsigned short* WabT_pk = (unsigned short*)(ws + 134742016);      //     524,288 B
  float* A_part           = (float*)(ws + 135266304);               //   4,194,304 B
  float* A_sm             = (float*)(ws + 139460608);               //     524,288 B
  float* Mpart            = (float*)(ws + 135266304);               //   overlays A_part
  float* abl              = (float*)(ws + 139984896);               //   64 KB scratch

  carp_wpack  <<<256,  256, 0, stream>>>(W1, Wa, Wb, W1T_pk, WabT_pk);
  carp_gemm1  <<<2048, 512, 0, stream>>>(h, W1T_pk, b1, h1_pk);
  carp_gemm2  <<<2048, 512, 0, stream>>>(h1_pk, WabT_pk, ba, bb, Wc, A_part);
  carp_softmax<<<16,   256, 0, stream>>>(A_part, bc, out + 5, A_sm);
  carp_mkernel<<<1024, 256, 0, stream>>>(h1_pk, A_sm, Mpart);
  carp_final  <<<1,    512, 0, stream>>>(Mpart, Wcls, bcls, out);

  // ---- diagnostic ablations (scratch-only; do not affect outputs)
  abl_gemm2<1><<<2048, 512, 0, stream>>>(h1_pk, WabT_pk, abl);  // no staging
  abl_gemm2<2><<<2048, 512, 0, stream>>>(h1_pk, WabT_pk, abl);  // no MFMA
  abl_gemm2<3><<<2048, 512, 0, stream>>>(h1_pk, WabT_pk, abl);  // no ds_read
  abl_gemm2<4><<<2048, 512, 0, stream>>>(h1_pk, WabT_pk, abl);  // barriers only
  abl_gemm2<5><<<2048, 512, 0, stream>>>(h1_pk, WabT_pk, abl);  // no barriers
  abl_bk64    <<<2048, 512, 0, stream>>>(h1_pk, WabT_pk, abl);  // BK=64 candidate
}

// Round 11
// 442.235 us; speedup vs baseline: 2.5848x; 2.5848x over previous
//
#include <hip/hip_runtime.h>
#include <math.h>

typedef short bf16x8 __attribute__((ext_vector_type(8)));
typedef float f32x4  __attribute__((ext_vector_type(4)));

#define GLOAD_LDS16(SRC, DST) \
  __builtin_amdgcn_global_load_lds((const __attribute__((address_space(1))) void*)(SRC), \
      (__attribute__((address_space(3))) void*)(DST), 16, 0, 0)

#define WAITVM(N) asm volatile("s_waitcnt vmcnt(" #N ")" ::: "memory")
#define WAITLGKM0 asm volatile("s_waitcnt lgkmcnt(0)" ::: "memory")
#define BARRIER() do { __builtin_amdgcn_s_barrier(); asm volatile("" ::: "memory"); } while (0)

__device__ __forceinline__ unsigned short f2bf(float f) {
  union { float f; unsigned u; } v; v.f = f;
  unsigned r = v.u + 0x7FFFu + ((v.u >> 16) & 1u);   // RNE
  return (unsigned short)(r >> 16);
}
__device__ __forceinline__ float bf2f(unsigned short s) {
  union { unsigned u; float f; } v; v.u = ((unsigned)s) << 16;
  return v.f;
}
__device__ __forceinline__ unsigned pk2bf(float lo, float hi) {
  unsigned r;
  asm("v_cvt_pk_bf16_f32 %0, %1, %2" : "=v"(r) : "v"(lo), "v"(hi));  // RNE
  return r;
}

// Granule layout: [128 x 32k] bf16 tile = 512 granules of 16B.
// granule g = s*64 + l: row = s*16 + (l&15), k8 = (l>>4)*8.
// h1_pk / W1T_pk / WabT_pk: panel P = rowpanel*16 + ktile (x512 granules).

// ---------------- weight pack (unchanged)
__global__ void carp_wpack(const float* __restrict__ W1, const float* __restrict__ Wa,
                           const float* __restrict__ Wb,
                           unsigned short* __restrict__ W1T_pk, unsigned short* __restrict__ WabT_pk) {
  int t = blockIdx.x * 256 + threadIdx.x;
  int mat = t >> 15;
  int gid = t & 32767;
  int g = gid & 511;
  int kt = (gid >> 9) & 15;
  int p = gid >> 13;
  int s = g >> 6, l = g & 63;
  int j = p * 128 + s * 16 + (l & 15);
  int k = kt * 32 + (l >> 4) * 8;
  unsigned short v[8];
  if (mat == 0) {
#pragma unroll
    for (int e = 0; e < 8; ++e) v[e] = f2bf(W1[(size_t)(k + e) * 512 + j]);
    *(uint4*)(W1T_pk + (size_t)gid * 8) = *(const uint4*)v;
  } else {
    int d = j >> 1;
    const float* Wx = (j & 1) ? Wb : Wa;
#pragma unroll
    for (int e = 0; e < 8; ++e) v[e] = f2bf(Wx[(size_t)(k + e) * 256 + d]);
    *(uint4*)(WabT_pk + (size_t)gid * 8) = *(const uint4*)v;
  }
}

// ---------------- GEMM1: bk64 structure. BM=256 BN=128, pair of 32k-tiles per iter.
// LDS 96KB: A dbuf [0,64K) ([buf][rp][ktile][512g]); B dbuf [64K,96K) ([buf][ktile][512g]).
__launch_bounds__(512, 2)
__global__ void carp_gemm1(const float* __restrict__ h, const unsigned short* __restrict__ W1T_pk,
                           const float* __restrict__ b1, unsigned short* __restrict__ h1_pk) {
  __shared__ __align__(16) unsigned short lds[49152];   // 96KB
  int bid0 = blockIdx.x;
  int bid = (bid0 & 7) * 256 + (bid0 >> 3);   // XCD remap, 2048 = 8*256
  int bn = bid & 3, bm = bid >> 2;
  int brow = bm * 256;
  int tid = threadIdx.x, lane = tid & 63, wid = tid >> 6;
  int wr = wid >> 1, wc = wid & 1;            // 4x2 waves: 64 rows x 64 cols each

  f32x4 acc[4][4] = {};
  float4 ar[8];

  // A loads: inst q: row = q*32 + r0, float4 chunk = (tid&15); coalesced 256B/row-group
  int r0 = tid >> 4;            // 0..31
  int chunk = tid & 15;         // k-chunk (4 floats) within 64-k pair
  const float* hbase = h + (size_t)(brow + r0) * 512 + chunk * 4;
  // ds_write const part: ktile = chunk>>3, kg = (chunk&7)>>1, half = chunk&1
  int aw_const = (chunk >> 3) * 8192 + (r0 >> 4) * 1024 + ((chunk & 7) >> 1) * 256
               + (r0 & 15) * 16 + (chunk & 1) * 8;

#define G1_LOADA(TP) do { \
  _Pragma("unroll") for (int q = 0; q < 8; ++q) \
    ar[q] = *(const float4*)(hbase + (size_t)(q * 32) * 512 + (TP) * 64); \
  } while (0)
#define G1_WRITEA(TP) do { \
  char* dstA = (char*)lds + ((TP) & 1) * 32768; \
  _Pragma("unroll") for (int q = 0; q < 8; ++q) { \
    uint2 wv; wv.x = pk2bf(ar[q].x, ar[q].y); wv.y = pk2bf(ar[q].z, ar[q].w); \
    *(uint2*)(dstA + (q >> 2) * 16384 + (q & 3) * 2048 + aw_const) = wv; \
  } } while (0)
#define G1_STAGEB(TP, BUF) do { \
  _Pragma("unroll") for (int t2 = 0; t2 < 2; ++t2) \
    GLOAD_LDS16(W1T_pk + ((size_t)(bn * 16 + (TP) * 2 + t2) * 512 + wid * 64 + lane) * 8, \
                (char*)lds + 65536 + (BUF) * 16384 + t2 * 8192 + (size_t)wid * 1024); \
  } while (0)

  // prologue
  G1_LOADA(0);
  WAITVM(0);
  G1_WRITEA(0);
  G1_STAGEB(0, 0);                  // outstanding: B0:2
  G1_LOADA(1);                      // + A1:8
  WAITLGKM0;

#pragma unroll
  for (int tp = 0; tp < 8; ++tp) {
    if (tp < 7) G1_STAGEB(tp + 1, (tp + 1) & 1);      // B(tp):2, A(tp+1):8, B(tp+1):2 = 12
    if (tp < 7) { WAITVM(10); } else { WAITVM(0); }   // B(tp) landed
    BARRIER();                                         // pair tp published
    const char* Abase = (const char*)lds + (tp & 1) * 32768;
    const char* Bbase = (const char*)lds + 65536 + (tp & 1) * 16384;
#pragma unroll
    for (int tt = 0; tt < 2; ++tt) {
      bf16x8 afr[4], bfr[4];
#pragma unroll
      for (int m = 0; m < 4; ++m) {
        int gs = wr * 4 + m;
        afr[m] = *(const bf16x8*)(Abase + (gs >> 3) * 16384 + tt * 8192
                                  + (size_t)((gs & 7) * 64 + lane) * 16);
      }
#pragma unroll
      for (int n = 0; n < 4; ++n)
        bfr[n] = *(const bf16x8*)(Bbase + tt * 8192 + (size_t)((wc * 4 + n) * 64 + lane) * 16);
#pragma unroll
      for (int m = 0; m < 4; ++m)
#pragma unroll
        for (int n = 0; n < 4; ++n)
          acc[m][n] = __builtin_amdgcn_mfma_f32_16x16x32_bf16(afr[m], bfr[n], acc[m][n], 0, 0, 0);
    }
    if (tp < 7) { WAITVM(2); G1_WRITEA(tp + 1); }     // A(tp+1) regs landed; B(tp+1) in flight
    if (tp < 6) G1_LOADA(tp + 2);                     // + A(tp+2):8
    WAITLGKM0;
    BARRIER();
  }
#undef G1_LOADA
#undef G1_WRITEA
#undef G1_STAGEB

  // epilogue: +b1, relu -> 64KB granule image [rp(2)][ktc(4)][512] -> contiguous h1_pk store
  unsigned short* img = lds;
#pragma unroll
  for (int n = 0; n < 4; ++n) {
    int cl = wc * 64 + n * 16 + (lane & 15);
    float bias = b1[bn * 128 + cl];
    int ktc = cl >> 5, c32 = cl & 31;
#pragma unroll
    for (int m = 0; m < 4; ++m)
#pragma unroll
      for (int j = 0; j < 4; ++j) {
        int r = wr * 64 + m * 16 + (lane >> 4) * 4 + j;
        float v = acc[m][n][j] + bias;
        v = v > 0.f ? v : 0.f;
        int gidx = (r >> 7) * 2048 + ktc * 512 + ((r & 127) >> 4) * 64 + (c32 >> 3) * 16 + (r & 15);
        img[(size_t)gidx * 8 + (c32 & 7)] = f2bf(v);
      }
  }
  __syncthreads();
#pragma unroll
  for (int i = 0; i < 8; ++i) {
    int g = i * 512 + tid;
    int P = (2 * bm + (g >> 11)) * 16 + bn * 4 + ((g >> 9) & 3);
    *(uint4*)(h1_pk + ((size_t)P * 512 + (g & 511)) * 8) = *(const uint4*)(img + (size_t)g * 8);
  }
}

// ---------------- GEMM2: bk64 structure (validated by R10 ablation), real epilogue
__launch_bounds__(512, 2)
__global__ void carp_gemm2(const unsigned short* __restrict__ h1_pk, const unsigned short* __restrict__ WabT_pk,
                           const float* __restrict__ ba, const float* __restrict__ bb,
                           const float* __restrict__ Wc, float* __restrict__ A_part) {
  __shared__ __align__(16) unsigned short lds[49152];   // 96KB: A dbuf [0,64K), B dbuf [64K,96K)
  int bid0 = blockIdx.x;
  int bid = (bid0 & 7) * 256 + (bid0 >> 3);
  int bn = bid & 3, bm = bid >> 2;
  int tid = threadIdx.x, lane = tid & 63, wid = tid >> 6;
  int wr = wid >> 1, wc = wid & 1;

  f32x4 acc[4][4] = {};

#define G2_STAGE(T32, HALF, BUF) do { \
  _Pragma("unroll") for (int q = 0; q < 2; ++q) { \
    int c = wid * 2 + q; \
    int P = (2 * bm + (c >> 3)) * 16 + (T32); \
    GLOAD_LDS16(h1_pk + ((size_t)P * 512 + (c & 7) * 64 + lane) * 8, \
                (char*)lds + (BUF) * 32768 + (HALF) * 16384 + (size_t)c * 1024); \
  } \
  GLOAD_LDS16(WabT_pk + ((size_t)(bn * 16 + (T32)) * 512 + wid * 64 + lane) * 8, \
              (char*)lds + 65536 + (BUF) * 16384 + (HALF) * 8192 + (size_t)wid * 1024); \
  } while (0)

  G2_STAGE(0, 0, 0); G2_STAGE(1, 1, 0);   // 6/wave outstanding

#pragma unroll
  for (int kt = 0; kt < 8; ++kt) {
    int cur = kt & 1, nxt = cur ^ 1;
    if (kt < 7) { G2_STAGE(2 * kt + 2, 0, nxt); G2_STAGE(2 * kt + 3, 1, nxt); }
    if (kt < 7) { WAITVM(6); } else { WAITVM(0); }   // pair kt landed; next pair in flight
    BARRIER();
#pragma unroll
    for (int tt = 0; tt < 2; ++tt) {
      const char* Ab = (const char*)lds + cur * 32768 + tt * 16384;
      const char* Bb = (const char*)lds + 65536 + cur * 16384 + tt * 8192;
      bf16x8 afr[4], bfr[4];
#pragma unroll
      for (int m = 0; m < 4; ++m)
        afr[m] = *(const bf16x8*)(Ab + (size_t)((wr * 4 + m) * 64 + lane) * 16);
#pragma unroll
      for (int n = 0; n < 4; ++n)
        bfr[n] = *(const bf16x8*)(Bb + (size_t)((wc * 4 + n) * 64 + lane) * 16);
#pragma unroll
      for (int m = 0; m < 4; ++m)
#pragma unroll
        for (int n = 0; n < 4; ++n)
          acc[m][n] = __builtin_amdgcn_mfma_f32_16x16x32_bf16(afr[m], bfr[n], acc[m][n], 0, 0, 0);
    }
    WAITLGKM0;
    BARRIER();
  }
#undef G2_STAGE

  int brow = bm * 256, bcol = bn * 128;
  float rowpart[4][4] = {};
#pragma unroll
  for (int n = 0; n < 4; ++n) {
    int cg = bcol + wc * 64 + n * 16 + (lane & 15);
    int d = cg >> 1;
    float bias = (cg & 1) ? bb[d] : ba[d];
    float wcd = Wc[d];
#pragma unroll
    for (int m = 0; m < 4; ++m)
#pragma unroll
      for (int j = 0; j < 4; ++j) {
        float v = acc[m][n][j] + bias;
        float av = (cg & 1) ? (1.f / (1.f + expf(-v))) : tanhf(v);
        float pv = av * __shfl_xor(av, 1, 64);   // a*g on both lanes of the pair
        rowpart[m][j] += pv * wcd;
      }
  }
#pragma unroll
  for (int m = 0; m < 4; ++m)
#pragma unroll
    for (int j = 0; j < 4; ++j) {
      float t = rowpart[m][j];
      t += __shfl_xor(t, 2, 64);
      t += __shfl_xor(t, 4, 64);
      t += __shfl_xor(t, 8, 64);
      rowpart[m][j] = t;
    }
  if ((lane & 15) == 0) {
    int slot = bn * 2 + wc;
#pragma unroll
    for (int m = 0; m < 4; ++m)
#pragma unroll
      for (int j = 0; j < 4; ++j) {
        int row = brow + wr * 64 + m * 16 + (lane >> 4) * 4 + j;
        A_part[(size_t)row * 8 + slot] = rowpart[m][j];
      }
  }
}

// ---------------- per-bag softmax (unchanged)
__global__ void carp_softmax(const float* __restrict__ A_part, const float* __restrict__ bc,
                             float* __restrict__ A_raw_out, float* __restrict__ A_sm) {
  __shared__ float sv[8192];
  __shared__ float red[256];
  int b = blockIdx.x, tid = threadIdx.x;
  float bcv = bc[0];
  float lmax = -1e30f;
  for (int i = tid; i < 8192; i += 256) {
    const float4* p = (const float4*)(A_part + (size_t)(b * 8192 + i) * 8);
    float4 x = p[0], y = p[1];
    float s = ((x.x + x.y) + (x.z + x.w)) + ((y.x + y.y) + (y.z + y.w)) + bcv;
    sv[i] = s;
    A_raw_out[b * 8192 + i] = s;
    lmax = fmaxf(lmax, s);
  }
  red[tid] = lmax;
  for (int s = 128; s > 0; s >>= 1) { __syncthreads(); if (tid < s) red[tid] = fmaxf(red[tid], red[tid + s]); }
  __syncthreads();
  float mx = red[0];
  __syncthreads();
  float lsum = 0.f;
  for (int i = tid; i < 8192; i += 256) {
    float e = expf(sv[i] - mx);
    sv[i] = e;
    lsum += e;
  }
  red[tid] = lsum;
  for (int s = 128; s > 0; s >>= 1) { __syncthreads(); if (tid < s) red[tid] += red[tid + s]; }
  __syncthreads();
  float inv = 1.f / red[0];
  for (int i = tid; i < 8192; i += 256) A_sm[b * 8192 + i] = sv[i] * inv;
}

// ---------------- M partials (unchanged)
__global__ void carp_mkernel(const unsigned short* __restrict__ h1_pk, const float* __restrict__ A_sm,
                             float* __restrict__ Mpart) {
  __shared__ float sw[128];
  int bm = blockIdx.x;
  int tid = threadIdx.x;
  if (tid < 128) sw[tid] = A_sm[bm * 128 + tid];
  __syncthreads();
  int l = tid & 63;
  float acc[4][8] = {};
#pragma unroll
  for (int tq = 0; tq < 4; ++tq) {
    int tt = (tid >> 6) * 4 + tq;
#pragma unroll
    for (int s = 0; s < 8; ++s) {
      const unsigned short* gp = h1_pk + ((size_t)(bm * 16 + tt) * 512 + s * 64 + l) * 8;
      uint4 raw = *(const uint4*)gp;
      const unsigned short* pv = (const unsigned short*)&raw;
      float w = sw[s * 16 + (l & 15)];
#pragma unroll
      for (int e = 0; e < 8; ++e) acc[tq][e] += w * bf2f(pv[e]);
    }
  }
#pragma unroll
  for (int tq = 0; tq < 4; ++tq)
#pragma unroll
    for (int e = 0; e < 8; ++e) {
      float t = acc[tq][e];
      t += __shfl_xor(t, 1, 64);
      t += __shfl_xor(t, 2, 64);
      t += __shfl_xor(t, 4, 64);
      t += __shfl_xor(t, 8, 64);
      acc[tq][e] = t;
    }
  if ((l & 15) == 0) {
    int cc = (l >> 4) & 3;
#pragma unroll
    for (int tq = 0; tq < 4; ++tq) {
      int tt = (tid >> 6) * 4 + tq;
      float* mp = Mpart + (size_t)bm * 512 + tt * 32 + cc * 8;
#pragma unroll
      for (int e = 0; e < 8; ++e) mp[e] = acc[tq][e];
    }
  }
}

// ---------------- final (unchanged)
__global__ void carp_final(const float* __restrict__ Mpart, const float* __restrict__ Wcls,
                           const float* __restrict__ bcls, float* __restrict__ out) {
  __shared__ float ctx[512];
  int t = threadIdx.x;
  float c = 0.f;
  for (int b = 0; b < 16; ++b) {
    float s = 0.f;
    for (int p = 0; p < 64; ++p) s += Mpart[((size_t)(b * 64 + p) << 9) + t];
    out[131077 + b * 512 + t] = s;
    c += s;
  }
  ctx[t] = c * (1.f / 16.f);
  __syncthreads();
  if (t < 64) {
    float p0 = 0.f, p1 = 0.f;
    for (int hh = t; hh < 512; hh += 64) {
      float cv = ctx[hh];
      p0 += cv * Wcls[hh * 2];
      p1 += cv * Wcls[hh * 2 + 1];
    }
    for (int m = 1; m < 64; m <<= 1) { p0 += __shfl_xor(p0, m, 64); p1 += __shfl_xor(p1, m, 64); }
    if (t == 0) {
      float l0 = p0 + bcls[0], l1 = p1 + bcls[1];
      out[0] = l0; out[1] = l1;
      float mx = fmaxf(l0, l1);
      float e0 = expf(l0 - mx), e1 = expf(l1 - mx);
      float s = e0 + e1;
      out[2] = e0 / s; out[3] = e1 / s;
      out[4] = (l1 > l0) ? 1.0f : 0.0f;
    }
  }
}

extern "C" void kernel_launch(void* const* d_in, const int* in_sizes, int n_in,
                              void* d_out, int out_size, void* d_ws, size_t ws_size,
                              hipStream_t stream) {
  const float* h    = (const float*)d_in[0];
  const float* W1   = (const float*)d_in[1];
  const float* b1   = (const float*)d_in[2];
  const float* Wa   = (const float*)d_in[3];
  const float* ba   = (const float*)d_in[4];
  const float* Wb   = (const float*)d_in[5];
  const float* bb   = (const float*)d_in[6];
  const float* Wc   = (const float*)d_in[7];
  const float* bc   = (const float*)d_in[8];
  const float* Wcls = (const float*)d_in[9];
  const float* bcls = (const float*)d_in[10];
  float* out = (float*)d_out;

  char* ws = (char*)d_ws;
  unsigned short* h1_pk   = (unsigned short*)(ws);                  // 134,217,728 B
  unsigned short* W1T_pk  = (unsigned short*)(ws + 134217728);      //     524,288 B
  unsigned short* WabT_pk = (unsigned short*)(ws + 134742016);      //     524,288 B
  float* A_part           = (float*)(ws + 135266304);               //   4,194,304 B
  float* A_sm             = (float*)(ws + 139460608);               //     524,288 B
  float* Mpart            = (float*)(ws + 135266304);               //   overlays A_part

  carp_wpack  <<<256,  256, 0, stream>>>(W1, Wa, Wb, W1T_pk, WabT_pk);
  carp_gemm1  <<<2048, 512, 0, stream>>>(h, W1T_pk, b1, h1_pk);
  carp_gemm2  <<<2048, 512, 0, stream>>>(h1_pk, WabT_pk, ba, bb, Wc, A_part);
  carp_softmax<<<16,   256, 0, stream>>>(A_part, bc, out + 5, A_sm);
  carp_mkernel<<<1024, 256, 0, stream>>>(h1_pk, A_sm, Mpart);
  carp_final  <<<1,    512, 0, stream>>>(Mpart, Wcls, bcls, out);
}